// Round 7
// baseline (278.506 us; speedup 1.0000x reference)
//
#include <hip/hip_runtime.h>

#define NUSERS 100000
#define NBOOKS 50000
#define HID 128
#define FEAT 256
#define EPR 500000
#define NEDGE (2 * EPR)

#define UBLK64 ((NUSERS + 63) / 64)         // 1563
#define BBLK64 ((NBOOKS + 63) / 64)         // 782
#define GH_BLOCKS (UBLK64 + BBLK64)         // 2345 (x512 edges >= NEDGE)
#define FILL_B ((NEDGE + 255) / 256)        // 3907
#define DIS_B ((NUSERS + 255) / 256)        // 391

typedef __attribute__((ext_vector_type(8))) short bf16x8;
typedef __attribute__((ext_vector_type(4))) float f32x4;

__device__ __forceinline__ unsigned short f2bf(float f) {
  union { float f; unsigned u; } v; v.f = f;
  unsigned r = v.u + 0x7FFFu + ((v.u >> 16) & 1u);   // RNE
  return (unsigned short)(r >> 16);
}
__device__ __forceinline__ float bf2f(unsigned short h) {
  union { unsigned u; float f; } v; v.u = ((unsigned)h) << 16;
  return v.f;
}
__device__ __forceinline__ unsigned pk2bf(float lo, float hi) {
  unsigned r;
  asm("v_cvt_pk_bf16_f32 %0, %1, %2" : "=v"(r) : "v"(lo), "v"(hi));
  return r;
}

// ---------------------------------------------------------------------------
__global__ void cast_w(const float* __restrict__ w0, const float* __restrict__ w1,
                       unsigned short* __restrict__ o0, unsigned short* __restrict__ o1)
{
  int i = blockIdx.x * 256 + threadIdx.x;
  if (i < HID * FEAT) { o0[i] = f2bf(w0[i]); o1[i] = f2bf(w1[i]); }
}

// ---------------------------------------------------------------------------
__device__ __forceinline__ void decode_edge(const int* __restrict__ rates,
                                            const int* __restrict__ impl,
                                            int i, int& u, int& bk)
{
  if (i < EPR) { u = rates[i]; bk = rates[EPR + i]; }
  else { int j = i - EPR; u = impl[j]; bk = impl[EPR + j]; }
}

// ---------------------------------------------------------------------------
// Every block: (1) issue its 512-edge chunk's histogram atomics up front
// (drain overlaps the GEMM), (2) GEMM a 64-row tile.
//
// GEMM: C = X @ W^T + b. 64 rows x K=256 fp32 staged once in LDS (64 KB) via
// global_load_lds w=16, ONE barrier, then 8 barrier-free K-steps.
// LDS layout: row r, 16B-unit c at phys (c ^ (r&7)) -> frag ds_reads have the
// same bank pattern R6 measured at 0 conflicts; staging source pre-swizzled
// (rule: linear dest + inverse-swizzled source + swizzled read).
// Wave wv owns rows [wv*16, wv*16+16): 1 A-frag x 8 B-frags per K-step.
// fp32->bf16 pack via v_cvt_pk_bf16_f32 (4 inst per frag).
// ---------------------------------------------------------------------------
__global__ __launch_bounds__(256) void gemm_hist(
    const float* __restrict__ Xu, const float* __restrict__ Xb,
    const unsigned short* __restrict__ Wu, const unsigned short* __restrict__ Wb,
    const float* __restrict__ bu, const float* __restrict__ bb,
    unsigned short* __restrict__ cu0b, float* __restrict__ outb,
    float* __restrict__ outu,
    const int* __restrict__ rates, const int* __restrict__ impl,
    int* __restrict__ degu, int* __restrict__ cntb,
    int* __restrict__ relpos)
{
  __shared__ float Asb[64 * 256];   // 64 KB
  const int bid = blockIdx.x;
  const int tid = threadIdx.x;

  // ---- edge-histogram prologue: 2 edges/thread, atomics issued early ----
  const int e0 = bid * 512 + tid;
  const int e1 = e0 + 256;
  const bool v0 = e0 < NEDGE, v1 = e1 < NEDGE;
  int p0 = 0, p1 = 0;
  if (v0) {
    int u, bk;
    decode_edge(rates, impl, e0, u, bk);
    p0 = atomicAdd(&cntb[bk], 1);
    atomicAdd(&degu[u], 1);
  }
  if (v1) {
    int u, bk;
    decode_edge(rates, impl, e1, u, bk);
    p1 = atomicAdd(&cntb[bk], 1);
    atomicAdd(&degu[u], 1);
  }

  // ---- GEMM identity ----
  const bool isU = bid < UBLK64;
  const float* __restrict__ X = isU ? Xu : Xb;
  const unsigned short* __restrict__ W = isU ? Wu : Wb;
  const float* __restrict__ bias = isU ? bu : bb;
  const int M  = isU ? NUSERS : NBOOKS;
  const int bm = (isU ? bid : bid - UBLK64) * 64;

  const int lane = tid & 63;
  const int wv   = tid >> 6;
  const int l15  = lane & 15, l4 = lane >> 4;

  // ---- stage 64 rows x 256 fp32 (4096 16B-units, 16 per thread) ----
#pragma unroll
  for (int rnd = 0; rnd < 16; ++rnd) {
    int o   = wv * 1024 + rnd * 64 + lane;
    int row = o >> 6;
    int pc  = o & 63;
    int lc  = pc ^ (row & 7);          // inverse swizzle on the SOURCE
    int gr  = bm + row; if (gr > M - 1) gr = M - 1;
    __builtin_amdgcn_global_load_lds(
        (const float*)&X[(size_t)gr * FEAT + lc * 4],
        &Asb[(size_t)(wv * 1024 + rnd * 64) * 4], 16, 0, 0);
  }
  __syncthreads();   // drains staging (and this block's atomics) once

  // ---- compute: 8 K-steps, no barriers ----
  f32x4 acc[8];
#pragma unroll
  for (int ni = 0; ni < 8; ++ni) acc[ni] = (f32x4)0.f;

  const int arow = wv * 16 + l15;
  const int m7   = l15 & 7;
#pragma unroll
  for (int ks = 0; ks < 8; ++ks) {
    bf16x8 bfr[8];
#pragma unroll
    for (int ni = 0; ni < 8; ++ni)
      bfr[ni] = *reinterpret_cast<const bf16x8*>(
          &W[(size_t)(ni * 16 + l15) * FEAT + ks * 32 + l4 * 8]);

    int lc0 = ks * 8 + l4 * 2;
    f32x4 a0 = *reinterpret_cast<const f32x4*>(&Asb[arow * 256 + ((lc0    ) ^ m7) * 4]);
    f32x4 a1 = *reinterpret_cast<const f32x4*>(&Asb[arow * 256 + ((lc0 + 1) ^ m7) * 4]);
    union { unsigned u32[4]; bf16x8 v; } au;
    au.u32[0] = pk2bf(a0[0], a0[1]);
    au.u32[1] = pk2bf(a0[2], a0[3]);
    au.u32[2] = pk2bf(a1[0], a1[1]);
    au.u32[3] = pk2bf(a1[2], a1[3]);

#pragma unroll
    for (int ni = 0; ni < 8; ++ni)
      acc[ni] = __builtin_amdgcn_mfma_f32_16x16x32_bf16(au.v, bfr[ni], acc[ni], 0, 0, 0);
  }

  // ---- epilogue ----
#pragma unroll
  for (int ni = 0; ni < 8; ++ni) {
    int col = ni * 16 + l15;
    float bj = bias[col];
#pragma unroll
    for (int j = 0; j < 4; ++j) {
      int rr = bm + wv * 16 + l4 * 4 + j;
      if (rr < M) {
        float vv = acc[ni][j] + bj;
        if (isU) {
          cu0b[(size_t)rr * HID + col] = f2bf(vv);
          if (rr >= NBOOKS) outu[(size_t)rr * HID + col] = vv * (1.0f / 3.0f);
        } else {
          outb[(size_t)rr * HID + col] = vv * (1.0f / 3.0f);
        }
      }
    }
  }

  // ---- histogram epilogue: store returned CSR slots ----
  if (v0) relpos[e0] = p0;
  if (v1) relpos[e1] = p1;
}

// ---------------------------------------------------------------------------
// fill_scatter (blocks [0, FILL_B)) + dis (blocks [FILL_B, FILL_B+DIS_B))
// ---------------------------------------------------------------------------
__global__ void fill_dis(const int* __restrict__ rates, const int* __restrict__ impl,
                         const int* __restrict__ offs,
                         const int* __restrict__ relpos,
                         int* __restrict__ brow,
                         const int* __restrict__ degu, const int* __restrict__ cntb,
                         float* __restrict__ dis)
{
  int b = blockIdx.x;
  if (b >= FILL_B) {
    int i = (b - FILL_B) * 256 + threadIdx.x;
    if (i < NUSERS) {
      int d = degu[i] + (i < NBOOKS ? cntb[i] : 0);
      dis[i] = (d > 0) ? rsqrtf((float)d) : 0.f;
    }
    return;
  }
  int i = b * 256 + threadIdx.x;
  if (i >= NEDGE) return;
  int u, bk;
  decode_edge(rates, impl, i, u, bk);
  brow[offs[bk] + relpos[i]] = u;
}

// ---------------------------------------------------------------------------
__global__ __launch_bounds__(1024) void scan_blocks(const int* __restrict__ counts,
                                                    int* __restrict__ offs,
                                                    int* __restrict__ bsum, int N)
{
  __shared__ int buf[1024];
  int t = threadIdx.x;
  int i = blockIdx.x * 1024 + t;
  int v = (i < N) ? counts[i] : 0;
  buf[t] = v;
  __syncthreads();
  for (int off = 1; off < 1024; off <<= 1) {
    int x = (t >= off) ? buf[t - off] : 0;
    __syncthreads();
    buf[t] += x;
    __syncthreads();
  }
  int incl = buf[t];
  if (i < N) offs[i] = incl - v;
  if (t == 1023) bsum[blockIdx.x] = incl;
}

__global__ void scan_totals(const int* __restrict__ bsum, int* __restrict__ bpre,
                            int* __restrict__ offs, int nb, int N)
{
  if (threadIdx.x == 0 && blockIdx.x == 0) {
    int run = 0;
    for (int b = 0; b < nb; ++b) { bpre[b] = run; run += bsum[b]; }
    offs[N] = run;
  }
}

__global__ void add_prefix(int* __restrict__ offs, const int* __restrict__ bpre, int N)
{
  int i = blockIdx.x * blockDim.x + threadIdx.x;
  if (i < N) offs[i] += bpre[i >> 10];
}

// ---------------------------------------------------------------------------
// Pull layer 1: wave per dest, 4 lane-groups of 16, 8 rows in flight.
// h1[c] = dis[c] * sum dis[u] * cu0[u].
// ---------------------------------------------------------------------------
__global__ __launch_bounds__(256) void pull1(const unsigned short* __restrict__ srcb,
    const int* __restrict__ offs, const int* __restrict__ brow,
    const float* __restrict__ dis, unsigned short* __restrict__ dstb)
{
  int c = (blockIdx.x << 2) + (threadIdx.x >> 6);
  if (c >= NBOOKS) return;
  const int lane = threadIdx.x & 63;
  const int g = lane >> 4, l = lane & 15;
  const int s = offs[c], e = offs[c + 1];

  float acc[8];
#pragma unroll
  for (int j = 0; j < 8; ++j) acc[j] = 0.f;

  int i = s + g;
  for (; i + 4 < e; i += 8) {
    int rr0 = brow[i], rr1 = brow[i + 4];
    float w0 = dis[rr0], w1 = dis[rr1];
    bf16x8 v0 = *reinterpret_cast<const bf16x8*>(&srcb[(size_t)rr0 * HID + l * 8]);
    bf16x8 v1 = *reinterpret_cast<const bf16x8*>(&srcb[(size_t)rr1 * HID + l * 8]);
#pragma unroll
    for (int j = 0; j < 8; ++j) acc[j] += w0 * bf2f((unsigned short)v0[j]);
#pragma unroll
    for (int j = 0; j < 8; ++j) acc[j] += w1 * bf2f((unsigned short)v1[j]);
  }
  if (i < e) {
    int rr = brow[i];
    float w = dis[rr];
    bf16x8 v = *reinterpret_cast<const bf16x8*>(&srcb[(size_t)rr * HID + l * 8]);
#pragma unroll
    for (int j = 0; j < 8; ++j) acc[j] += w * bf2f((unsigned short)v[j]);
  }

#pragma unroll
  for (int j = 0; j < 8; ++j) {
    acc[j] += __shfl_xor(acc[j], 16, 64);
    acc[j] += __shfl_xor(acc[j], 32, 64);
  }
  if (g == 0) {
    float db = dis[c];
    bf16x8 o;
#pragma unroll
    for (int j = 0; j < 8; ++j) o[j] = (short)f2bf(db * acc[j]);
    *reinterpret_cast<bf16x8*>(&dstb[(size_t)c * HID + l * 8]) = o;
  }
}

// Layer 2 + final mean (dests < NBOOKS). Branchless clamped gathers of h1b.
__global__ __launch_bounds__(256) void pull2_final(const unsigned short* __restrict__ h1b,
    const int* __restrict__ offs, const int* __restrict__ brow,
    const float* __restrict__ dis, const unsigned short* __restrict__ cu0b,
    float* __restrict__ outu)
{
  int c = (blockIdx.x << 2) + (threadIdx.x >> 6);
  if (c >= NBOOKS) return;
  const int lane = threadIdx.x & 63;
  const int g = lane >> 4, l = lane & 15;
  const int s = offs[c], e = offs[c + 1];

  float acc[8];
#pragma unroll
  for (int j = 0; j < 8; ++j) acc[j] = 0.f;

  int i = s + g;
  for (; i + 4 < e; i += 8) {
    int rr0 = brow[i], rr1 = brow[i + 4];
    int rc0 = rr0 < NBOOKS ? rr0 : 0;
    int rc1 = rr1 < NBOOKS ? rr1 : 0;
    float w0 = rr0 < NBOOKS ? dis[rr0] : 0.f;
    float w1 = rr1 < NBOOKS ? dis[rr1] : 0.f;
    bf16x8 v0 = *reinterpret_cast<const bf16x8*>(&h1b[(size_t)rc0 * HID + l * 8]);
    bf16x8 v1 = *reinterpret_cast<const bf16x8*>(&h1b[(size_t)rc1 * HID + l * 8]);
#pragma unroll
    for (int j = 0; j < 8; ++j) acc[j] += w0 * bf2f((unsigned short)v0[j]);
#pragma unroll
    for (int j = 0; j < 8; ++j) acc[j] += w1 * bf2f((unsigned short)v1[j]);
  }
  if (i < e) {
    int rr = brow[i];
    int rc = rr < NBOOKS ? rr : 0;
    float w = rr < NBOOKS ? dis[rr] : 0.f;
    bf16x8 v = *reinterpret_cast<const bf16x8*>(&h1b[(size_t)rc * HID + l * 8]);
#pragma unroll
    for (int j = 0; j < 8; ++j) acc[j] += w * bf2f((unsigned short)v[j]);
  }

#pragma unroll
  for (int j = 0; j < 8; ++j) {
    acc[j] += __shfl_xor(acc[j], 16, 64);
    acc[j] += __shfl_xor(acc[j], 32, 64);
  }
  if (g == 0) {
    float db = dis[c];
    size_t idx = (size_t)c * HID + l * 8;
    bf16x8 c0 = *reinterpret_cast<const bf16x8*>(&cu0b[idx]);
    bf16x8 h1 = *reinterpret_cast<const bf16x8*>(&h1b[idx]);
    float r[8];
#pragma unroll
    for (int j = 0; j < 8; ++j)
      r[j] = (bf2f((unsigned short)c0[j]) + bf2f((unsigned short)h1[j]) + db * acc[j]) * (1.0f / 3.0f);
    *reinterpret_cast<float4*>(&outu[idx])     = make_float4(r[0], r[1], r[2], r[3]);
    *reinterpret_cast<float4*>(&outu[idx + 4]) = make_float4(r[4], r[5], r[6], r[7]);
  }
}

// ---------------------------------------------------------------------------
extern "C" void kernel_launch(void* const* d_in, const int* in_sizes, int n_in,
                              void* d_out, int out_size, void* d_ws, size_t ws_size,
                              hipStream_t stream)
{
  const float* user_x = (const float*)d_in[0];
  const float* book_x = (const float*)d_in[1];
  const float* user_W = (const float*)d_in[2];
  const float* user_b = (const float*)d_in[3];
  const float* book_W = (const float*)d_in[4];
  const float* book_b = (const float*)d_in[5];
  const int*   rates  = (const int*)d_in[6];
  const int*   impl   = (const int*)d_in[7];

  float* out      = (float*)d_out;
  float* out_user = out;
  float* out_book = out + (size_t)NUSERS * HID;

  char* p = (char*)d_ws;
  auto carve = [&](size_t bytes) -> void* {
    void* r = (void*)p;
    p += (bytes + 255) & ~(size_t)255;
    return r;
  };
  unsigned short* cu0b   = (unsigned short*)carve((size_t)NUSERS * HID * 2);
  unsigned short* h1b    = (unsigned short*)carve((size_t)NBOOKS * HID * 2);
  unsigned short* wub    = (unsigned short*)carve((size_t)HID * FEAT * 2);
  unsigned short* wbb    = (unsigned short*)carve((size_t)HID * FEAT * 2);
  int*   degu   = (int*)carve((size_t)NUSERS * 4);
  int*   cntb   = (int*)carve((size_t)NBOOKS * 4);
  float* dis    = (float*)carve((size_t)NUSERS * 4);
  int*   offs   = (int*)carve((size_t)(NBOOKS + 2) * 4);
  int*   bsum   = (int*)carve(256 * 4);
  int*   bpre   = (int*)carve(256 * 4);
  int*   relpos = (int*)carve((size_t)NEDGE * 4);
  int*   brow   = (int*)carve((size_t)NEDGE * 4);

  hipMemsetAsync(degu, 0, (size_t)NUSERS * 4, stream);
  hipMemsetAsync(cntb, 0, (size_t)NBOOKS * 4, stream);

  cast_w<<<(HID * FEAT + 255) / 256, 256, 0, stream>>>(user_W, book_W, wub, wbb);

  // fused GEMM (one-barrier LDS-staged MFMA) + per-block edge histogram
  gemm_hist<<<GH_BLOCKS, 256, 0, stream>>>(
      user_x, book_x, wub, wbb, user_b, book_b,
      cu0b, out_book, out_user, rates, impl, degu, cntb, relpos);

  const int nb = (NBOOKS + 1023) / 1024;
  scan_blocks<<<nb, 1024, 0, stream>>>(cntb, offs, bsum, NBOOKS);
  scan_totals<<<1, 64, 0, stream>>>(bsum, bpre, offs, nb, NBOOKS);
  add_prefix<<<(NBOOKS + 255) / 256, 256, 0, stream>>>(offs, bpre, NBOOKS);

  // CSR fill (atomic-free scatter) + dis, fused
  fill_dis<<<FILL_B + DIS_B, 256, 0, stream>>>(rates, impl, offs, relpos, brow,
                                               degu, cntb, dis);

  // propagation (dests < NBOOKS), layer 2 fuses final mean
  pull1<<<(NBOOKS + 3) / 4, 256, 0, stream>>>(cu0b, offs, brow, dis, h1b);
  pull2_final<<<(NBOOKS + 3) / 4, 256, 0, stream>>>(h1b, offs, brow, dis, cu0b, out_user);
}

// Round 8
// 275.508 us; speedup vs baseline: 1.0109x; 1.0109x over previous
//
#include <hip/hip_runtime.h>

#define NUSERS 100000
#define NBOOKS 50000
#define HID 128
#define FEAT 256
#define EPR 500000
#define NEDGE (2 * EPR)

#define UBLK64 ((NUSERS + 63) / 64)         // 1563
#define BBLK64 ((NBOOKS + 63) / 64)         // 782
#define GH_BLOCKS (UBLK64 + BBLK64)         // 2345 (x512 edges >= NEDGE)
#define FILL_B ((NEDGE + 255) / 256)        // 3907
#define DIS_B ((NUSERS + 255) / 256)        // 391

typedef __attribute__((ext_vector_type(8))) short bf16x8;
typedef __attribute__((ext_vector_type(4))) float f32x4;

__device__ __forceinline__ unsigned short f2bf(float f) {
  union { float f; unsigned u; } v; v.f = f;
  unsigned r = v.u + 0x7FFFu + ((v.u >> 16) & 1u);   // RNE
  return (unsigned short)(r >> 16);
}
__device__ __forceinline__ float bf2f(unsigned short h) {
  union { unsigned u; float f; } v; v.u = ((unsigned)h) << 16;
  return v.f;
}
__device__ __forceinline__ unsigned pk2bf(float lo, float hi) {
  unsigned r;
  asm("v_cvt_pk_bf16_f32 %0, %1, %2" : "=v"(r) : "v"(lo), "v"(hi));
  return r;
}

// ---------------------------------------------------------------------------
__global__ void cast_w(const float* __restrict__ w0, const float* __restrict__ w1,
                       unsigned short* __restrict__ o0, unsigned short* __restrict__ o1)
{
  int i = blockIdx.x * 256 + threadIdx.x;
  if (i < HID * FEAT) { o0[i] = f2bf(w0[i]); o1[i] = f2bf(w1[i]); }
}

// ---------------------------------------------------------------------------
__device__ __forceinline__ void decode_edge(const int* __restrict__ rates,
                                            const int* __restrict__ impl,
                                            int i, int& u, int& bk)
{
  if (i < EPR) { u = rates[i]; bk = rates[EPR + i]; }
  else { int j = i - EPR; u = impl[j]; bk = impl[EPR + j]; }
}

// ---------------------------------------------------------------------------
// BARRIER-FREE fused GEMM + histogram.
// Each of 4 waves independently owns 16 rows: stages them (half-K = 16 rows x
// 128 fp32 = 8 KB private LDS) via global_load_lds, waits WAVE-LOCALLY
// (vmcnt), computes 4 K-steps (1 A-frag x 8 B-frags each), restages the
// second K-half, computes. No __syncthreads anywhere.
// LDS: [wave][16 rows][32 units of 16B], phys unit = logical ^ (row&15)
// (R6-verified 0-conflict class), applied by pre-swizzling the GLOBAL source.
// Histogram atomics are issued at the VERY END (vmcnt retires in issue order,
// so issuing them earlier would gate the staging waits on the global atomic
// stream -- the R7 failure). Their latency overlaps other waves' GEMM.
// ---------------------------------------------------------------------------
__global__ __launch_bounds__(256) void gemm_hist(
    const float* __restrict__ Xu, const float* __restrict__ Xb,
    const unsigned short* __restrict__ Wu, const unsigned short* __restrict__ Wb,
    const float* __restrict__ bu, const float* __restrict__ bb,
    unsigned short* __restrict__ cu0b, float* __restrict__ outb,
    float* __restrict__ outu,
    const int* __restrict__ rates, const int* __restrict__ impl,
    int* __restrict__ degu, int* __restrict__ cntb,
    int* __restrict__ relpos)
{
  __shared__ float Asb[4][2048];   // 4 waves x 8 KB = 32 KB
  const int bid = blockIdx.x;
  const int tid = threadIdx.x;
  const int lane = tid & 63;
  const int wv   = tid >> 6;
  const int l15  = lane & 15, l4 = lane >> 4;

  const bool isU = bid < UBLK64;
  const float* __restrict__ X = isU ? Xu : Xb;
  const unsigned short* __restrict__ W = isU ? Wu : Wb;
  const float* __restrict__ bias = isU ? bu : bb;
  const int M    = isU ? NUSERS : NBOOKS;
  const int bm   = (isU ? bid : bid - UBLK64) * 64;
  const int wrow = bm + wv * 16;

  float* wbase = &Asb[wv][0];

  f32x4 acc[8];
#pragma unroll
  for (int ni = 0; ni < 8; ++ni) acc[ni] = (f32x4)0.f;

#pragma unroll
  for (int h = 0; h < 2; ++h) {
    if (h) {
      // our own frag reads of this region must complete before overwrite
      asm volatile("s_waitcnt lgkmcnt(0)" ::: "memory");
      __builtin_amdgcn_sched_barrier(0);
    }
    // stage 16 rows x 128 fp32: 512 16B-units, 8 rounds of 64 lanes
#pragma unroll
    for (int rnd = 0; rnd < 8; ++rnd) {
      int o = rnd * 64 + lane;
      int r = o >> 5;                 // 0..15
      int c = o & 31;                 // phys unit within row
      int lc = c ^ r;                 // logical unit (inverse swizzle on src)
      int gr = wrow + r; if (gr > M - 1) gr = M - 1;
      __builtin_amdgcn_global_load_lds(
          (const float*)&X[(size_t)gr * FEAT + h * 128 + lc * 4],
          wbase + rnd * 256, 16, 0, 0);
    }
    asm volatile("s_waitcnt vmcnt(0)" ::: "memory");
    __builtin_amdgcn_sched_barrier(0);

#pragma unroll
    for (int ks = 0; ks < 4; ++ks) {
      const int kg = h * 4 + ks;
      bf16x8 bfr[8];
#pragma unroll
      for (int ni = 0; ni < 8; ++ni)
        bfr[ni] = *reinterpret_cast<const bf16x8*>(
            &W[(size_t)(ni * 16 + l15) * FEAT + kg * 32 + l4 * 8]);

      int u0 = (ks * 8 + l4 * 2) ^ l15;
      int u1 = (ks * 8 + l4 * 2 + 1) ^ l15;
      f32x4 a0 = *reinterpret_cast<const f32x4*>(&wbase[(l15 * 32 + u0) * 4]);
      f32x4 a1 = *reinterpret_cast<const f32x4*>(&wbase[(l15 * 32 + u1) * 4]);
      union { unsigned u32[4]; bf16x8 v; } au;
      au.u32[0] = pk2bf(a0[0], a0[1]);
      au.u32[1] = pk2bf(a0[2], a0[3]);
      au.u32[2] = pk2bf(a1[0], a1[1]);
      au.u32[3] = pk2bf(a1[2], a1[3]);

#pragma unroll
      for (int ni = 0; ni < 8; ++ni)
        acc[ni] = __builtin_amdgcn_mfma_f32_16x16x32_bf16(au.v, bfr[ni], acc[ni], 0, 0, 0);
    }
  }

  // ---- C epilogue ----
#pragma unroll
  for (int ni = 0; ni < 8; ++ni) {
    int col = ni * 16 + l15;
    float bj = bias[col];
#pragma unroll
    for (int j = 0; j < 4; ++j) {
      int rr = wrow + l4 * 4 + j;
      if (rr < M) {
        float vv = acc[ni][j] + bj;
        if (isU) {
          cu0b[(size_t)rr * HID + col] = f2bf(vv);
          if (rr >= NBOOKS) outu[(size_t)rr * HID + col] = vv * (1.0f / 3.0f);
        } else {
          outb[(size_t)rr * HID + col] = vv * (1.0f / 3.0f);
        }
      }
    }
  }

  // ---- histogram LAST: atomic latency overlaps other waves' GEMM ----
  const int e0 = bid * 512 + tid;
  const int e1 = e0 + 256;
  if (e0 < NEDGE) {
    int u, bk;
    decode_edge(rates, impl, e0, u, bk);
    int p0 = atomicAdd(&cntb[bk], 1);
    atomicAdd(&degu[u], 1);
    relpos[e0] = p0;
  }
  if (e1 < NEDGE) {
    int u, bk;
    decode_edge(rates, impl, e1, u, bk);
    int p1 = atomicAdd(&cntb[bk], 1);
    atomicAdd(&degu[u], 1);
    relpos[e1] = p1;
  }
}

// ---------------------------------------------------------------------------
// fill_scatter (blocks [0, FILL_B)) + dis (blocks [FILL_B, FILL_B+DIS_B))
// ---------------------------------------------------------------------------
__global__ void fill_dis(const int* __restrict__ rates, const int* __restrict__ impl,
                         const int* __restrict__ offs,
                         const int* __restrict__ relpos,
                         int* __restrict__ brow,
                         const int* __restrict__ degu, const int* __restrict__ cntb,
                         float* __restrict__ dis)
{
  int b = blockIdx.x;
  if (b >= FILL_B) {
    int i = (b - FILL_B) * 256 + threadIdx.x;
    if (i < NUSERS) {
      int d = degu[i] + (i < NBOOKS ? cntb[i] : 0);
      dis[i] = (d > 0) ? rsqrtf((float)d) : 0.f;
    }
    return;
  }
  int i = b * 256 + threadIdx.x;
  if (i >= NEDGE) return;
  int u, bk;
  decode_edge(rates, impl, i, u, bk);
  brow[offs[bk] + relpos[i]] = u;
}

// ---------------------------------------------------------------------------
__global__ __launch_bounds__(1024) void scan_blocks(const int* __restrict__ counts,
                                                    int* __restrict__ offs,
                                                    int* __restrict__ bsum, int N)
{
  __shared__ int buf[1024];
  int t = threadIdx.x;
  int i = blockIdx.x * 1024 + t;
  int v = (i < N) ? counts[i] : 0;
  buf[t] = v;
  __syncthreads();
  for (int off = 1; off < 1024; off <<= 1) {
    int x = (t >= off) ? buf[t - off] : 0;
    __syncthreads();
    buf[t] += x;
    __syncthreads();
  }
  int incl = buf[t];
  if (i < N) offs[i] = incl - v;
  if (t == 1023) bsum[blockIdx.x] = incl;
}

__global__ void scan_totals(const int* __restrict__ bsum, int* __restrict__ bpre,
                            int* __restrict__ offs, int nb, int N)
{
  if (threadIdx.x == 0 && blockIdx.x == 0) {
    int run = 0;
    for (int b = 0; b < nb; ++b) { bpre[b] = run; run += bsum[b]; }
    offs[N] = run;
  }
}

__global__ void add_prefix(int* __restrict__ offs, const int* __restrict__ bpre, int N)
{
  int i = blockIdx.x * blockDim.x + threadIdx.x;
  if (i < N) offs[i] += bpre[i >> 10];
}

// ---------------------------------------------------------------------------
// Pull layer 1: wave per dest, 4 lane-groups of 16, 8 rows in flight.
// h1[c] = dis[c] * sum dis[u] * cu0[u].
// ---------------------------------------------------------------------------
__global__ __launch_bounds__(256) void pull1(const unsigned short* __restrict__ srcb,
    const int* __restrict__ offs, const int* __restrict__ brow,
    const float* __restrict__ dis, unsigned short* __restrict__ dstb)
{
  int c = (blockIdx.x << 2) + (threadIdx.x >> 6);
  if (c >= NBOOKS) return;
  const int lane = threadIdx.x & 63;
  const int g = lane >> 4, l = lane & 15;
  const int s = offs[c], e = offs[c + 1];

  float acc[8];
#pragma unroll
  for (int j = 0; j < 8; ++j) acc[j] = 0.f;

  int i = s + g;
  for (; i + 4 < e; i += 8) {
    int rr0 = brow[i], rr1 = brow[i + 4];
    float w0 = dis[rr0], w1 = dis[rr1];
    bf16x8 v0 = *reinterpret_cast<const bf16x8*>(&srcb[(size_t)rr0 * HID + l * 8]);
    bf16x8 v1 = *reinterpret_cast<const bf16x8*>(&srcb[(size_t)rr1 * HID + l * 8]);
#pragma unroll
    for (int j = 0; j < 8; ++j) acc[j] += w0 * bf2f((unsigned short)v0[j]);
#pragma unroll
    for (int j = 0; j < 8; ++j) acc[j] += w1 * bf2f((unsigned short)v1[j]);
  }
  if (i < e) {
    int rr = brow[i];
    float w = dis[rr];
    bf16x8 v = *reinterpret_cast<const bf16x8*>(&srcb[(size_t)rr * HID + l * 8]);
#pragma unroll
    for (int j = 0; j < 8; ++j) acc[j] += w * bf2f((unsigned short)v[j]);
  }

#pragma unroll
  for (int j = 0; j < 8; ++j) {
    acc[j] += __shfl_xor(acc[j], 16, 64);
    acc[j] += __shfl_xor(acc[j], 32, 64);
  }
  if (g == 0) {
    float db = dis[c];
    bf16x8 o;
#pragma unroll
    for (int j = 0; j < 8; ++j) o[j] = (short)f2bf(db * acc[j]);
    *reinterpret_cast<bf16x8*>(&dstb[(size_t)c * HID + l * 8]) = o;
  }
}

// Layer 2 + final mean (dests < NBOOKS). Branchless clamped gathers of h1b.
__global__ __launch_bounds__(256) void pull2_final(const unsigned short* __restrict__ h1b,
    const int* __restrict__ offs, const int* __restrict__ brow,
    const float* __restrict__ dis, const unsigned short* __restrict__ cu0b,
    float* __restrict__ outu)
{
  int c = (blockIdx.x << 2) + (threadIdx.x >> 6);
  if (c >= NBOOKS) return;
  const int lane = threadIdx.x & 63;
  const int g = lane >> 4, l = lane & 15;
  const int s = offs[c], e = offs[c + 1];

  float acc[8];
#pragma unroll
  for (int j = 0; j < 8; ++j) acc[j] = 0.f;

  int i = s + g;
  for (; i + 4 < e; i += 8) {
    int rr0 = brow[i], rr1 = brow[i + 4];
    int rc0 = rr0 < NBOOKS ? rr0 : 0;
    int rc1 = rr1 < NBOOKS ? rr1 : 0;
    float w0 = rr0 < NBOOKS ? dis[rr0] : 0.f;
    float w1 = rr1 < NBOOKS ? dis[rr1] : 0.f;
    bf16x8 v0 = *reinterpret_cast<const bf16x8*>(&h1b[(size_t)rc0 * HID + l * 8]);
    bf16x8 v1 = *reinterpret_cast<const bf16x8*>(&h1b[(size_t)rc1 * HID + l * 8]);
#pragma unroll
    for (int j = 0; j < 8; ++j) acc[j] += w0 * bf2f((unsigned short)v0[j]);
#pragma unroll
    for (int j = 0; j < 8; ++j) acc[j] += w1 * bf2f((unsigned short)v1[j]);
  }
  if (i < e) {
    int rr = brow[i];
    int rc = rr < NBOOKS ? rr : 0;
    float w = rr < NBOOKS ? dis[rr] : 0.f;
    bf16x8 v = *reinterpret_cast<const bf16x8*>(&h1b[(size_t)rc * HID + l * 8]);
#pragma unroll
    for (int j = 0; j < 8; ++j) acc[j] += w * bf2f((unsigned short)v[j]);
  }

#pragma unroll
  for (int j = 0; j < 8; ++j) {
    acc[j] += __shfl_xor(acc[j], 16, 64);
    acc[j] += __shfl_xor(acc[j], 32, 64);
  }
  if (g == 0) {
    float db = dis[c];
    size_t idx = (size_t)c * HID + l * 8;
    bf16x8 c0 = *reinterpret_cast<const bf16x8*>(&cu0b[idx]);
    bf16x8 h1 = *reinterpret_cast<const bf16x8*>(&h1b[idx]);
    float r[8];
#pragma unroll
    for (int j = 0; j < 8; ++j)
      r[j] = (bf2f((unsigned short)c0[j]) + bf2f((unsigned short)h1[j]) + db * acc[j]) * (1.0f / 3.0f);
    *reinterpret_cast<float4*>(&outu[idx])     = make_float4(r[0], r[1], r[2], r[3]);
    *reinterpret_cast<float4*>(&outu[idx + 4]) = make_float4(r[4], r[5], r[6], r[7]);
  }
}

// ---------------------------------------------------------------------------
extern "C" void kernel_launch(void* const* d_in, const int* in_sizes, int n_in,
                              void* d_out, int out_size, void* d_ws, size_t ws_size,
                              hipStream_t stream)
{
  const float* user_x = (const float*)d_in[0];
  const float* book_x = (const float*)d_in[1];
  const float* user_W = (const float*)d_in[2];
  const float* user_b = (const float*)d_in[3];
  const float* book_W = (const float*)d_in[4];
  const float* book_b = (const float*)d_in[5];
  const int*   rates  = (const int*)d_in[6];
  const int*   impl   = (const int*)d_in[7];

  float* out      = (float*)d_out;
  float* out_user = out;
  float* out_book = out + (size_t)NUSERS * HID;

  char* p = (char*)d_ws;
  auto carve = [&](size_t bytes) -> void* {
    void* r = (void*)p;
    p += (bytes + 255) & ~(size_t)255;
    return r;
  };
  unsigned short* cu0b   = (unsigned short*)carve((size_t)NUSERS * HID * 2);
  unsigned short* h1b    = (unsigned short*)carve((size_t)NBOOKS * HID * 2);
  unsigned short* wub    = (unsigned short*)carve((size_t)HID * FEAT * 2);
  unsigned short* wbb    = (unsigned short*)carve((size_t)HID * FEAT * 2);
  int*   degu   = (int*)carve((size_t)NUSERS * 4);
  int*   cntb   = (int*)carve((size_t)NBOOKS * 4);
  float* dis    = (float*)carve((size_t)NUSERS * 4);
  int*   offs   = (int*)carve((size_t)(NBOOKS + 2) * 4);
  int*   bsum   = (int*)carve(256 * 4);
  int*   bpre   = (int*)carve(256 * 4);
  int*   relpos = (int*)carve((size_t)NEDGE * 4);
  int*   brow   = (int*)carve((size_t)NEDGE * 4);

  hipMemsetAsync(degu, 0, (size_t)NUSERS * 4, stream);
  hipMemsetAsync(cntb, 0, (size_t)NBOOKS * 4, stream);

  cast_w<<<(HID * FEAT + 255) / 256, 256, 0, stream>>>(user_W, book_W, wub, wbb);

  // barrier-free fused GEMM + tail-issued edge histogram
  gemm_hist<<<GH_BLOCKS, 256, 0, stream>>>(
      user_x, book_x, wub, wbb, user_b, book_b,
      cu0b, out_book, out_user, rates, impl, degu, cntb, relpos);

  const int nb = (NBOOKS + 1023) / 1024;
  scan_blocks<<<nb, 1024, 0, stream>>>(cntb, offs, bsum, NBOOKS);
  scan_totals<<<1, 64, 0, stream>>>(bsum, bpre, offs, nb, NBOOKS);
  add_prefix<<<(NBOOKS + 255) / 256, 256, 0, stream>>>(offs, bpre, NBOOKS);

  // CSR fill (atomic-free scatter) + dis, fused
  fill_dis<<<FILL_B + DIS_B, 256, 0, stream>>>(rates, impl, offs, relpos, brow,
                                               degu, cntb, dis);

  // propagation (dests < NBOOKS), layer 2 fuses final mean
  pull1<<<(NBOOKS + 3) / 4, 256, 0, stream>>>(cu0b, offs, brow, dis, h1b);
  pull2_final<<<(NBOOKS + 3) / 4, 256, 0, stream>>>(h1b, offs, brow, dis, cu0b, out_user);
}